// Round 6
// baseline (207.810 us; speedup 1.0000x reference)
//
#include <hip/hip_runtime.h>

// Problem constants
#define SRC_N   (512 * 512)
#define IMG_W   1024
#define IMG_HW  (1024 * 1024)
#define BATCH   4

#define CHUNKS_PER_B   128
#define K1_BLOCKS      (BATCH * CHUNKS_PER_B)    // 512
#define K1_THREADS     512
#define PTS_PER_CHUNK  2048
#define NBINS          1024                      // 32x32 grid of 32x32-px tiles
#define PREFIX_STRIDE  (NBINS + 1)
#define SENT           0xFFFFFFFFu
#define CAP            (SRC_N + 4 * NBINS)       // sorted capacity per batch (padding)

// ws layout (all tables fully rewritten every call; no memsets needed)
#define STAGED_BYTES ((size_t)K1_BLOCKS * PTS_PER_CHUNK * 16)          // 16 MB
#define SORTED_OFF   STAGED_BYTES
#define SORTED_BYTES ((size_t)BATCH * CAP * 16)                        // ~16.25 MB
#define PF_OFF       (SORTED_OFF + SORTED_BYTES)
#define PF_BYTES     ((size_t)K1_BLOCKS * PREFIX_STRIDE * 4)           // ~2.1 MB
#define HC_OFF       ((PF_OFF + PF_BYTES + 255) & ~(size_t)255)
#define HC_BYTES     ((size_t)BATCH * NBINS * CHUNKS_PER_B * 4)        // 2 MB
#define TOT_OFF      (HC_OFF + HC_BYTES)
#define TOT_BYTES    ((size_t)BATCH * NBINS * 4)
#define BASE_OFF     (TOT_OFF + TOT_BYTES)
#define BASE_BYTES   ((size_t)BATCH * NBINS * 4)
#define CORNER_OFF   (BASE_OFF + BASE_BYTES)

// ---------------------------------------------------------------------------
// K1: classify + per-chunk bin (proven R5 structure). Adds bin-major
// histogram write for the cross-chunk scan. Zero global atomics.
// ---------------------------------------------------------------------------
__global__ void __launch_bounds__(512)
bin_kernel(const float* __restrict__ uv, const float* __restrict__ pos,
           float4* __restrict__ staged, unsigned* __restrict__ prefix,
           unsigned* __restrict__ histcum, float* __restrict__ corner_out) {
    const int blk   = blockIdx.x;          // 0..511
    const int b     = blk >> 7;
    const int chunk = blk & (CHUNKS_PER_B - 1);
    const int t     = threadIdx.x;

    __shared__ unsigned s_hist[NBINS];
    __shared__ unsigned s_cur[NBINS];
    __shared__ unsigned s_sum[K1_THREADS];
    __shared__ float    s_corner[12];

    s_hist[t] = 0; s_hist[t + 512] = 0;
    if (t < 12) s_corner[t] = 0.0f;
    __syncthreads();

    const float* uvb = uv  + (size_t)b * 14 * SRC_N;
    const float* pb  = pos + (size_t)b * 3  * SRC_N;
    const int n0 = chunk * PTS_PER_CHUNK + t * 4;

    const float4 pxv = *(const float4*)&pb [n0];
    const float4 pyv = *(const float4*)&pb [SRC_N + n0];
    const float4 ux  = *(const float4*)&uvb[n0];
    const float4 uy  = *(const float4*)&uvb[SRC_N + n0];
    const float4 ov  = *(const float4*)&uvb[10 * SRC_N + n0];
    const float4 rv  = *(const float4*)&uvb[11 * SRC_N + n0];
    const float4 gv  = *(const float4*)&uvb[12 * SRC_N + n0];
    const float4 bv  = *(const float4*)&uvb[13 * SRC_N + n0];

    const float X[4]  = {pxv.x + ux.x, pxv.y + ux.y, pxv.z + ux.z, pxv.w + ux.w};
    const float Y[4]  = {pyv.x + uy.x, pyv.y + uy.y, pyv.z + uy.z, pyv.w + uy.w};
    const float O[4]  = {ov.x, ov.y, ov.z, ov.w};
    const float CR[4] = {rv.x, rv.y, rv.z, rv.w};
    const float CG[4] = {gv.x, gv.y, gv.z, gv.w};
    const float CB[4] = {bv.x, bv.y, bv.z, bv.w};

    unsigned packed[4];
    float R[4], G[4], B[4];

#pragma unroll
    for (int j = 0; j < 4; ++j) {
        // truncating cast (matches .astype(int32)), then clamp
        int px = (int)((X[j] + 1.0f) * 512.0f);
        int py = (int)((Y[j] + 1.0f) * 512.0f);
        px = min(max(px, 0), IMG_W - 1);
        py = min(max(py, 0), IMG_W - 1);

        const float opac = 1.0f / (1.0f + __expf(-O[j]));
        R[j] = CR[j] * opac; G[j] = CG[j] * opac; B[j] = CB[j] * opac;

        const bool xe = (px == 0) | (px == IMG_W - 1);
        const bool ye = (py == 0) | (py == IMG_W - 1);
        if (xe & ye) {
            const int ci = ((py != 0) ? 2 : 0) + ((px != 0) ? 1 : 0);
            atomicAdd(&s_corner[ci * 3 + 0], R[j]);
            atomicAdd(&s_corner[ci * 3 + 1], G[j]);
            atomicAdd(&s_corner[ci * 3 + 2], B[j]);
            packed[j] = SENT;
        } else {
            const int bin = ((py >> 5) << 5) | (px >> 5);
            atomicAdd(&s_hist[bin], 1u);
            packed[j] = ((unsigned)bin << 10) | ((unsigned)(py & 31) << 5)
                      | (unsigned)(px & 31);
        }
    }
    __syncthreads();

    // pair-scan: thread t owns bins 2t, 2t+1
    const unsigned h0 = s_hist[2 * t], h1 = s_hist[2 * t + 1];
    s_sum[t] = h0 + h1;
    __syncthreads();
    for (int d = 1; d < K1_THREADS; d <<= 1) {
        const unsigned v = (t >= d) ? s_sum[t - d] : 0u;
        __syncthreads();
        s_sum[t] += v;
        __syncthreads();
    }
    const unsigned incl = s_sum[t];
    const unsigned e0 = incl - h0 - h1;
    s_cur[2 * t]     = e0;
    s_cur[2 * t + 1] = e0 + h0;
    unsigned* pf = prefix + (size_t)blk * PREFIX_STRIDE;
    pf[2 * t]     = e0;
    pf[2 * t + 1] = e0 + h0;
    if (t == K1_THREADS - 1) pf[NBINS] = incl;
    if (t < 12) corner_out[blk * 12 + t] = s_corner[t];

    // bin-major histogram for the cross-chunk scan
    for (int k = t; k < NBINS; k += 512)
        histcum[(size_t)(b * NBINS + k) * CHUNKS_PER_B + chunk] = s_hist[k];
    __syncthreads();

    // ordered payload scatter into the chunk's private staged region
    float4* pbase = staged + (size_t)blk * PTS_PER_CHUNK;
#pragma unroll
    for (int j = 0; j < 4; ++j) {
        if (packed[j] != SENT) {
            const int bin = packed[j] >> 10;
            const unsigned p = atomicAdd(&s_cur[bin], 1u);
            pbase[p] = make_float4(__uint_as_float(packed[j]), R[j], G[j], B[j]);
        }
    }
}

// ---------------------------------------------------------------------------
// S1: one wave per (batch,bin): exclusive scan of 128 chunk counts in-place
// (histcum becomes cross-chunk offsets), tile total -> totals.
// ---------------------------------------------------------------------------
__global__ void __launch_bounds__(256)
scan_chunks(unsigned* __restrict__ histcum, unsigned* __restrict__ totals) {
    const int g    = blockIdx.x * 4 + (threadIdx.x >> 6);   // (b,bin) wave id
    const int lane = threadIdx.x & 63;
    unsigned* row = histcum + (size_t)g * CHUNKS_PER_B;

    const unsigned h0 = row[lane], h1 = row[64 + lane];
    unsigned i0 = h0, i1 = h1;
#pragma unroll
    for (int off = 1; off < 64; off <<= 1) {
        const unsigned n0 = __shfl_up(i0, off, 64);
        const unsigned n1 = __shfl_up(i1, off, 64);
        if (lane >= off) { i0 += n0; i1 += n1; }
    }
    const unsigned tot0 = __shfl(i0, 63, 64);
    const unsigned tot1 = __shfl(i1, 63, 64);
    row[lane]      = i0 - h0;
    row[64 + lane] = i1 - h1 + tot0;
    if (lane == 0) totals[g] = tot0 + tot1;
}

// ---------------------------------------------------------------------------
// S2: per-batch exclusive scan of (64B-padded) tile totals -> tile bases.
// ---------------------------------------------------------------------------
__global__ void __launch_bounds__(1024)
scan_bins(const unsigned* __restrict__ totals, unsigned* __restrict__ base) {
    const int b = blockIdx.x, t = threadIdx.x;
    __shared__ unsigned s[NBINS];
    const unsigned len  = totals[b * NBINS + t];
    const unsigned plen = (len + 3u) & ~3u;     // pad segment to 64B
    s[t] = plen;
    __syncthreads();
    for (int d = 1; d < NBINS; d <<= 1) {
        const unsigned v = (t >= d) ? s[t - d] : 0u;
        __syncthreads();
        s[t] += v;
        __syncthreads();
    }
    base[b * NBINS + t] = s[t] - plen;
}

// ---------------------------------------------------------------------------
// K1c: pass-through scatter into globally tile-sorted order.
// dst = base[bin] + cum[bin][chunk] + (p - pf[chunk][bin])  (one LDS lookup).
// Linear staged reads; scattered (short-run) writes.
// ---------------------------------------------------------------------------
__global__ void __launch_bounds__(512)
scatter_sorted(const float4* __restrict__ staged, const unsigned* __restrict__ prefix,
               const unsigned* __restrict__ histcum, const unsigned* __restrict__ base,
               float4* __restrict__ sorted) {
    const int blk = blockIdx.x;
    const int b   = blk >> 7;
    const int c   = blk & (CHUNKS_PER_B - 1);
    const int t   = threadIdx.x;

    __shared__ int arr[NBINS];
    const unsigned* pfr = prefix + (size_t)blk * PREFIX_STRIDE;
    for (int k = t; k < NBINS; k += 512)
        arr[k] = (int)base[b * NBINS + k]
               + (int)histcum[(size_t)(b * NBINS + k) * CHUNKS_PER_B + c]
               - (int)pfr[k];
    __syncthreads();

    const int total = pfr[NBINS];
    const float4* sb = staged + (size_t)blk * PTS_PER_CHUNK;
    float4* dstb = sorted + (size_t)b * CAP;
    for (int p = t; p < total; p += 512) {
        const float4 v = sb[p];
        const unsigned bin = __float_as_uint(v.x) >> 10;
        dstb[arr[bin] + p] = v;
    }
}

// ---------------------------------------------------------------------------
// K2: one 256-thread block per (batch, 32x32 tile). CONTIGUOUS segment read,
// LDS accumulate, corner fold, dense clipped float4 stores. 12KB LDS.
// ---------------------------------------------------------------------------
__global__ void __launch_bounds__(256)
accum_kernel(const float4* __restrict__ sorted, const unsigned* __restrict__ totals,
             const unsigned* __restrict__ base, const float* __restrict__ corner_out,
             float* __restrict__ out) {
    const int bg   = blockIdx.x;           // 0..4095
    const int b    = bg >> 10;
    const int tile = bg & (NBINS - 1);
    const int ty   = tile >> 5, tx = tile & 31;
    const int t    = threadIdx.x;

    __shared__ float acc[3 * 1024];        // 12 KB
    float4* acc4 = (float4*)acc;
    const float4 z4 = make_float4(0.f, 0.f, 0.f, 0.f);
    acc4[t] = z4; acc4[256 + t] = z4; acc4[512 + t] = z4;
    __syncthreads();

    const unsigned cnt = totals[b * NBINS + tile];
    const float4* seg = sorted + (size_t)b * CAP + base[b * NBINS + tile];
    for (unsigned i = t; i < cnt; i += 256) {
        const float4 v = seg[i];
        const unsigned idx = __float_as_uint(v.x) & 1023u;
        atomicAdd(&acc[idx],        v.y);
        atomicAdd(&acc[1024 + idx], v.z);
        atomicAdd(&acc[2048 + idx], v.w);
    }

    // corner fold (4 corner tiles per batch), parallel over 128 chunks
    const bool cx = (tx == 0) | (tx == 31);
    const bool cy = (ty == 0) | (ty == 31);
    if (cx & cy & (t < CHUNKS_PER_B)) {
        const int ci   = ((ty == 31) ? 2 : 0) + ((tx == 31) ? 1 : 0);
        const int cpix = ((ty == 31) ? 992 : 0) + ((tx == 31) ? 31 : 0);
        const float* cp = corner_out + (size_t)(b * CHUNKS_PER_B + t) * 12 + ci * 3;
        atomicAdd(&acc[cpix],        cp[0]);
        atomicAdd(&acc[1024 + cpix], cp[1]);
        atomicAdd(&acc[2048 + cpix], cp[2]);
    }
    __syncthreads();

    // dense clipped store: thread t -> 4 consecutive pixels x 3 channels
    float* ob = out + (size_t)b * 3 * IMG_HW;
    const int ly  = t >> 3;
    const int lx4 = (t & 7) << 2;
    const int gy  = ty * 32 + ly;
    const int gx  = tx * 32 + lx4;
#pragma unroll
    for (int c = 0; c < 3; ++c) {
        float4 v = acc4[c * 256 + t];
        v.x = fminf(fmaxf(v.x, 0.f), 1.f);
        v.y = fminf(fmaxf(v.y, 0.f), 1.f);
        v.z = fminf(fmaxf(v.z, 0.f), 1.f);
        v.w = fminf(fmaxf(v.w, 0.f), 1.f);
        *(float4*)(ob + (size_t)c * IMG_HW + (size_t)gy * IMG_W + gx) = v;
    }
}

extern "C" void kernel_launch(void* const* d_in, const int* in_sizes, int n_in,
                              void* d_out, int out_size, void* d_ws, size_t ws_size,
                              hipStream_t stream) {
    const float* uv  = (const float*)d_in[0];   // (4,14,512,512)
    const float* pos = (const float*)d_in[1];   // (4,3,512,512)
    float* out = (float*)d_out;                 // (4,3,1024,1024)

    char* ws = (char*)d_ws;
    float4*   staged     = (float4*)(ws);
    float4*   sorted     = (float4*)(ws + SORTED_OFF);
    unsigned* prefix     = (unsigned*)(ws + PF_OFF);
    unsigned* histcum    = (unsigned*)(ws + HC_OFF);
    unsigned* totals     = (unsigned*)(ws + TOT_OFF);
    unsigned* base       = (unsigned*)(ws + BASE_OFF);
    float*    corner_out = (float*)(ws + CORNER_OFF);

    bin_kernel   <<<K1_BLOCKS, K1_THREADS, 0, stream>>>(uv, pos, staged, prefix,
                                                        histcum, corner_out);
    scan_chunks  <<<BATCH * NBINS / 4, 256, 0, stream>>>(histcum, totals);
    scan_bins    <<<BATCH, 1024, 0, stream>>>(totals, base);
    scatter_sorted<<<K1_BLOCKS, K1_THREADS, 0, stream>>>(staged, prefix, histcum,
                                                         base, sorted);
    accum_kernel <<<BATCH * NBINS, 256, 0, stream>>>(sorted, totals, base,
                                                     corner_out, out);
}

// Round 7
// 136.239 us; speedup vs baseline: 1.5253x; 1.5253x over previous
//
#include <hip/hip_runtime.h>

// Problem constants
#define SRC_N   (512 * 512)
#define IMG_W   1024
#define IMG_HW  (1024 * 1024)
#define BATCH   4

#define CHUNKS_PER_B   128
#define K1_BLOCKS      (BATCH * CHUNKS_PER_B)    // 512
#define K1_THREADS     512
#define PTS_PER_CHUNK  2048
// Bins: 0..255 = 4-row bands (y-interior pixels); 256..287 = row-0 px-segments
// (32 px each); 288..319 = row-1023 px-segments. Corners -> LDS side path.
#define NBINS          320
#define PSTRIDE        (NBINS + 1)
#define SENT           0xFFFFFFFFu

// ws layout (all tables fully rewritten every call; no memsets needed)
#define STAGED_BYTES ((size_t)K1_BLOCKS * PTS_PER_CHUNK * 16)          // 16 MB
#define PF_OFF       STAGED_BYTES
#define PF_BYTES     ((size_t)K1_BLOCKS * PSTRIDE * 4)                 // 657 KB
#define CO_OFF       ((PF_OFF + PF_BYTES + 255) & ~(size_t)255)
#define CO_BYTES     ((size_t)K1_BLOCKS * 12 * 4)                      // 24 KB
#define EB_OFF       ((CO_OFF + CO_BYTES + 255) & ~(size_t)255)
// edgebuf: [b][row(2)][c(3)][1024] floats = 96 KB, fully written by edge_kernel

// ---------------------------------------------------------------------------
// K1: classify + per-chunk bin (R6 structure, 320 bins). Zero global atomics.
// ---------------------------------------------------------------------------
__global__ void __launch_bounds__(512)
bin_kernel(const float* __restrict__ uv, const float* __restrict__ pos,
           float4* __restrict__ staged, unsigned* __restrict__ prefix,
           float* __restrict__ corner_out) {
    const int blk   = blockIdx.x;          // 0..511
    const int b     = blk >> 7;
    const int chunk = blk & (CHUNKS_PER_B - 1);
    const int t     = threadIdx.x;

    __shared__ unsigned s_hist[512];       // bins 320..511 stay zero
    __shared__ unsigned s_tmp[512];
    __shared__ unsigned s_cur[NBINS];
    __shared__ float    s_corner[12];

    s_hist[t] = 0;
    if (t < 12) s_corner[t] = 0.0f;
    __syncthreads();

    const float* uvb = uv  + (size_t)b * 14 * SRC_N;
    const float* pb  = pos + (size_t)b * 3  * SRC_N;
    const int n0 = chunk * PTS_PER_CHUNK + t * 4;

    const float4 pxv = *(const float4*)&pb [n0];
    const float4 pyv = *(const float4*)&pb [SRC_N + n0];
    const float4 ux  = *(const float4*)&uvb[n0];
    const float4 uy  = *(const float4*)&uvb[SRC_N + n0];
    const float4 ov  = *(const float4*)&uvb[10 * SRC_N + n0];
    const float4 rv  = *(const float4*)&uvb[11 * SRC_N + n0];
    const float4 gv  = *(const float4*)&uvb[12 * SRC_N + n0];
    const float4 bv  = *(const float4*)&uvb[13 * SRC_N + n0];

    const float X[4]  = {pxv.x + ux.x, pxv.y + ux.y, pxv.z + ux.z, pxv.w + ux.w};
    const float Y[4]  = {pyv.x + uy.x, pyv.y + uy.y, pyv.z + uy.z, pyv.w + uy.w};
    const float O[4]  = {ov.x, ov.y, ov.z, ov.w};
    const float CR[4] = {rv.x, rv.y, rv.z, rv.w};
    const float CG[4] = {gv.x, gv.y, gv.z, gv.w};
    const float CB[4] = {bv.x, bv.y, bv.z, bv.w};

    unsigned packed[4];
    float R[4], G[4], B[4];

#pragma unroll
    for (int j = 0; j < 4; ++j) {
        // truncating cast (matches .astype(int32)), then clamp
        int px = (int)((X[j] + 1.0f) * 512.0f);
        int py = (int)((Y[j] + 1.0f) * 512.0f);
        px = min(max(px, 0), IMG_W - 1);
        py = min(max(py, 0), IMG_W - 1);

        const float opac = 1.0f / (1.0f + __expf(-O[j]));
        R[j] = CR[j] * opac; G[j] = CG[j] * opac; B[j] = CB[j] * opac;

        const bool xe = (px == 0) | (px == IMG_W - 1);
        const bool ye = (py == 0) | (py == IMG_W - 1);
        if (xe & ye) {
            const int ci = ((py != 0) ? 2 : 0) + ((px != 0) ? 1 : 0);
            atomicAdd(&s_corner[ci * 3 + 0], R[j]);
            atomicAdd(&s_corner[ci * 3 + 1], G[j]);
            atomicAdd(&s_corner[ci * 3 + 2], B[j]);
            packed[j] = SENT;
        } else {
            int bin;
            if (ye) bin = 256 + ((py != 0) ? 32 : 0) + (px >> 5);  // edge seg
            else    bin = py >> 2;                                 // 4-row band
            atomicAdd(&s_hist[bin], 1u);
            packed[j] = ((unsigned)bin << 12) | ((unsigned)(py & 3) << 10)
                      | (unsigned)px;
        }
    }
    __syncthreads();

    // Hillis-Steele scan over 512 entries (1 bin/thread)
    const unsigned h = s_hist[t];
    s_tmp[t] = h;
    __syncthreads();
    for (int d = 1; d < 512; d <<= 1) {
        const unsigned v = (t >= d) ? s_tmp[t - d] : 0u;
        __syncthreads();
        s_tmp[t] += v;
        __syncthreads();
    }
    const unsigned excl = s_tmp[t] - h;
    unsigned* pf = prefix + (size_t)blk * PSTRIDE;
    if (t < NBINS) { s_cur[t] = excl; pf[t] = excl; }
    if (t == NBINS) pf[NBINS] = excl;           // total (bins>=320 empty)
    if (t < 12) corner_out[blk * 12 + t] = s_corner[t];
    __syncthreads();

    // cur-ordered scatter into the chunk's private staged region
    float4* pbase = staged + (size_t)blk * PTS_PER_CHUNK;
#pragma unroll
    for (int j = 0; j < 4; ++j) {
        if (packed[j] != SENT) {
            const int bin = packed[j] >> 12;
            const unsigned p = atomicAdd(&s_cur[bin], 1u);
            pbase[p] = make_float4(__uint_as_float(packed[j]), R[j], G[j], B[j]);
        }
    }
}

// ---------------------------------------------------------------------------
// K2e: one block per (batch, row in {0,1023}, 32-px segment). Accumulates the
// segment's edge payloads + corner partials into 96 floats, stores edgebuf.
// ---------------------------------------------------------------------------
__global__ void __launch_bounds__(256)
edge_kernel(const float4* __restrict__ staged, const unsigned* __restrict__ prefix,
            const float* __restrict__ corner_out, float* __restrict__ edgebuf) {
    const int blk = blockIdx.x;            // b*64 + row*32 + seg
    const int b   = blk >> 6;
    const int row = (blk >> 5) & 1;
    const int seg = blk & 31;
    const int bin = 256 + row * 32 + seg;
    const int t   = threadIdx.x;

    __shared__ float    acc[96];           // [c][lx]
    __shared__ unsigned rs[128], re[128];

    if (t < 96) acc[t] = 0.0f;
    if (t < 128) rs[t]        = prefix[(size_t)(b * 128 + t) * PSTRIDE + bin];
    else         re[t - 128]  = prefix[(size_t)(b * 128 + (t - 128)) * PSTRIDE + bin + 1];
    __syncthreads();

    const int chunk = t & 127;
    const int sub   = t >> 7;
    const float4* pbase = staged + (size_t)(b * 128 + chunk) * PTS_PER_CHUNK;
    for (unsigned i = rs[chunk] + sub; i < re[chunk]; i += 2) {
        const float4 v = pbase[i];
        const int lx = (int)(__float_as_uint(v.x) & 1023u) - seg * 32;
        atomicAdd(&acc[lx],      v.y);
        atomicAdd(&acc[32 + lx], v.z);
        atomicAdd(&acc[64 + lx], v.w);
    }

    // corner fold: seg 0 owns px=0, seg 31 owns px=1023 of this row
    if (((seg == 0) | (seg == 31)) & (t < 128)) {
        const int ci = row * 2 + ((seg == 31) ? 1 : 0);
        const int lx = (seg == 31) ? 31 : 0;
        const float* cp = corner_out + (size_t)(b * 128 + t) * 12 + ci * 3;
        atomicAdd(&acc[lx],      cp[0]);
        atomicAdd(&acc[32 + lx], cp[1]);
        atomicAdd(&acc[64 + lx], cp[2]);
    }
    __syncthreads();

    if (t < 96) {
        const int c = t >> 5, lx = t & 31;
        edgebuf[((size_t)(b * 2 + row) * 3 + c) * 1024 + seg * 32 + lx] = acc[c * 32 + lx];
    }
}

// ---------------------------------------------------------------------------
// K2: one 256-thread block per (batch, 4-row band). 48 KB LDS stripe.
// Gather per-chunk runs, LDS-atomic accumulate, fold edgebuf for bands
// 0/255, then FULLY LINEAR clipped float4 stores (3 x 16 KB contiguous).
// ---------------------------------------------------------------------------
__global__ void __launch_bounds__(256)
accum_kernel(const float4* __restrict__ staged, const unsigned* __restrict__ prefix,
             const float* __restrict__ edgebuf, float* __restrict__ out) {
    const int bg   = blockIdx.x;           // 0..1023
    const int b    = bg >> 8;
    const int band = bg & 255;
    const int t    = threadIdx.x;

    __shared__ float    acc[3 * 4096];     // [c][ly*1024+px], 48 KB
    __shared__ unsigned rs[128], re[128];

    float4* acc4 = (float4*)acc;
    const float4 z4 = make_float4(0.f, 0.f, 0.f, 0.f);
#pragma unroll
    for (int i = 0; i < 12; ++i) acc4[i * 256 + t] = z4;
    if (t < 128) rs[t]       = prefix[(size_t)(b * 128 + t) * PSTRIDE + band];
    else         re[t - 128] = prefix[(size_t)(b * 128 + (t - 128)) * PSTRIDE + band + 1];
    __syncthreads();

    const int chunk = t & 127;
    const int sub   = t >> 7;
    const float4* pbase = staged + (size_t)(b * 128 + chunk) * PTS_PER_CHUNK;
    for (unsigned i = rs[chunk] + sub; i < re[chunk]; i += 2) {
        const float4 v = pbase[i];
        const unsigned key = __float_as_uint(v.x);
        const unsigned idx = ((key >> 10) & 3u) * 1024 + (key & 1023u);
        atomicAdd(&acc[idx],        v.y);
        atomicAdd(&acc[4096 + idx], v.z);
        atomicAdd(&acc[8192 + idx], v.w);
    }
    __syncthreads();

    // fold edge rows: band 0 row ly=0 <- edgebuf row0; band 255 ly=3 <- row1023
    if (band == 0) {
        const float4* eb = (const float4*)(edgebuf + (size_t)(b * 2 + 0) * 3 * 1024);
        for (int k = t; k < 768; k += 256) {
            const int c = k >> 8, q = k & 255;
            const float4 e = eb[k];
            float4 a = acc4[c * 1024 + q];            // ly=0 row
            a.x += e.x; a.y += e.y; a.z += e.z; a.w += e.w;
            acc4[c * 1024 + q] = a;
        }
    } else if (band == 255) {
        const float4* eb = (const float4*)(edgebuf + (size_t)(b * 2 + 1) * 3 * 1024);
        for (int k = t; k < 768; k += 256) {
            const int c = k >> 8, q = k & 255;
            const float4 e = eb[k];
            float4 a = acc4[c * 1024 + 768 + q];      // ly=3 row
            a.x += e.x; a.y += e.y; a.z += e.z; a.w += e.w;
            acc4[c * 1024 + 768 + q] = a;
        }
    }
    __syncthreads();

    // fully linear clipped stores: per (c,k), consecutive t -> consecutive 16B
    float* ob = out + (size_t)b * 3 * IMG_HW + (size_t)band * 4096;
#pragma unroll
    for (int c = 0; c < 3; ++c) {
        float4* dst = (float4*)(ob + (size_t)c * IMG_HW);
#pragma unroll
        for (int k = 0; k < 4; ++k) {
            float4 v = acc4[c * 1024 + k * 256 + t];
            v.x = fminf(fmaxf(v.x, 0.f), 1.f);
            v.y = fminf(fmaxf(v.y, 0.f), 1.f);
            v.z = fminf(fmaxf(v.z, 0.f), 1.f);
            v.w = fminf(fmaxf(v.w, 0.f), 1.f);
            dst[k * 256 + t] = v;
        }
    }
}

extern "C" void kernel_launch(void* const* d_in, const int* in_sizes, int n_in,
                              void* d_out, int out_size, void* d_ws, size_t ws_size,
                              hipStream_t stream) {
    const float* uv  = (const float*)d_in[0];   // (4,14,512,512)
    const float* pos = (const float*)d_in[1];   // (4,3,512,512)
    float* out = (float*)d_out;                 // (4,3,1024,1024)

    char* ws = (char*)d_ws;
    float4*   staged     = (float4*)(ws);
    unsigned* prefix     = (unsigned*)(ws + PF_OFF);
    float*    corner_out = (float*)(ws + CO_OFF);
    float*    edgebuf    = (float*)(ws + EB_OFF);

    bin_kernel  <<<K1_BLOCKS, K1_THREADS, 0, stream>>>(uv, pos, staged, prefix,
                                                       corner_out);
    edge_kernel <<<BATCH * 64, 256, 0, stream>>>(staged, prefix, corner_out,
                                                 edgebuf);
    accum_kernel<<<BATCH * 256, 256, 0, stream>>>(staged, prefix, edgebuf, out);
}

// Round 9
// 131.366 us; speedup vs baseline: 1.5819x; 1.0371x over previous
//
#include <hip/hip_runtime.h>

// Problem constants
#define SRC_N   (512 * 512)
#define IMG_W   1024
#define IMG_HW  (1024 * 1024)
#define BATCH   4

#define CHUNKS_PER_B   128
#define K1_BLOCKS      (BATCH * CHUNKS_PER_B)    // 512
#define K1_THREADS     512
#define PTS_PER_CHUNK  2048
// Bins: 0..255 = 4-row bands (y-interior pixels); 256..287 = row-0 px-segments
// (32 px each); 288..319 = row-1023 px-segments. Corners -> LDS side path.
#define NBINS          320
#define PSTRIDE        (NBINS + 1)
#define SENT           0xFFFFFFFFu

// native vector type for nontemporal builtins (HIP float4 is a class type)
typedef float nfloat4 __attribute__((ext_vector_type(4)));

// ws layout (all tables fully rewritten every call; no memsets needed)
#define STAGED_BYTES ((size_t)K1_BLOCKS * PTS_PER_CHUNK * 16)          // 16 MB
#define PF_OFF       STAGED_BYTES
#define PF_BYTES     ((size_t)K1_BLOCKS * PSTRIDE * 4)                 // 657 KB
#define CO_OFF       ((PF_OFF + PF_BYTES + 255) & ~(size_t)255)
#define CO_BYTES     ((size_t)K1_BLOCKS * 12 * 4)                      // 24 KB
#define EB_OFF       ((CO_OFF + CO_BYTES + 255) & ~(size_t)255)
// edgebuf: [b][row(2)][c(3)][1024] floats = 96 KB

// ---------------------------------------------------------------------------
// K1: classify + per-chunk bin. Hierarchical scan: per-wave shfl inclusive
// scan + cross-wave offset from 8 LDS wave totals -> 4 barriers total
// (was 21 with Hillis-Steele). Zero global atomics.
// ---------------------------------------------------------------------------
__global__ void __launch_bounds__(512)
bin_kernel(const float* __restrict__ uv, const float* __restrict__ pos,
           float4* __restrict__ staged, unsigned* __restrict__ prefix,
           float* __restrict__ corner_out) {
    const int blk   = blockIdx.x;          // 0..511
    const int b     = blk >> 7;
    const int chunk = blk & (CHUNKS_PER_B - 1);
    const int t     = threadIdx.x;
    const int lane  = t & 63;
    const int wave  = t >> 6;              // 0..7

    __shared__ unsigned s_hist[512];       // bins 320..511 stay zero
    __shared__ unsigned s_cur[NBINS];
    __shared__ unsigned s_wsum[8];
    __shared__ float    s_corner[12];

    s_hist[t] = 0;
    if (t < 12) s_corner[t] = 0.0f;
    __syncthreads();                                               // B1

    const float* uvb = uv  + (size_t)b * 14 * SRC_N;
    const float* pb  = pos + (size_t)b * 3  * SRC_N;
    const int n0 = chunk * PTS_PER_CHUNK + t * 4;

    const float4 pxv = *(const float4*)&pb [n0];
    const float4 pyv = *(const float4*)&pb [SRC_N + n0];
    const float4 ux  = *(const float4*)&uvb[n0];
    const float4 uy  = *(const float4*)&uvb[SRC_N + n0];
    const float4 ov  = *(const float4*)&uvb[10 * SRC_N + n0];
    const float4 rv  = *(const float4*)&uvb[11 * SRC_N + n0];
    const float4 gv  = *(const float4*)&uvb[12 * SRC_N + n0];
    const float4 bv  = *(const float4*)&uvb[13 * SRC_N + n0];

    const float X[4]  = {pxv.x + ux.x, pxv.y + ux.y, pxv.z + ux.z, pxv.w + ux.w};
    const float Y[4]  = {pyv.x + uy.x, pyv.y + uy.y, pyv.z + uy.z, pyv.w + uy.w};
    const float O[4]  = {ov.x, ov.y, ov.z, ov.w};
    const float CR[4] = {rv.x, rv.y, rv.z, rv.w};
    const float CG[4] = {gv.x, gv.y, gv.z, gv.w};
    const float CB[4] = {bv.x, bv.y, bv.z, bv.w};

    unsigned packed[4];
    float R[4], G[4], B[4];

#pragma unroll
    for (int j = 0; j < 4; ++j) {
        // truncating cast (matches .astype(int32)), then clamp
        int px = (int)((X[j] + 1.0f) * 512.0f);
        int py = (int)((Y[j] + 1.0f) * 512.0f);
        px = min(max(px, 0), IMG_W - 1);
        py = min(max(py, 0), IMG_W - 1);

        const float opac = 1.0f / (1.0f + __expf(-O[j]));
        R[j] = CR[j] * opac; G[j] = CG[j] * opac; B[j] = CB[j] * opac;

        const bool xe = (px == 0) | (px == IMG_W - 1);
        const bool ye = (py == 0) | (py == IMG_W - 1);
        if (xe & ye) {
            const int ci = ((py != 0) ? 2 : 0) + ((px != 0) ? 1 : 0);
            atomicAdd(&s_corner[ci * 3 + 0], R[j]);
            atomicAdd(&s_corner[ci * 3 + 1], G[j]);
            atomicAdd(&s_corner[ci * 3 + 2], B[j]);
            packed[j] = SENT;
        } else {
            int bin;
            if (ye) bin = 256 + ((py != 0) ? 32 : 0) + (px >> 5);  // edge seg
            else    bin = py >> 2;                                 // 4-row band
            atomicAdd(&s_hist[bin], 1u);
            packed[j] = ((unsigned)bin << 12) | ((unsigned)(py & 3) << 10)
                      | (unsigned)px;
        }
    }
    __syncthreads();                                               // B2

    // hierarchical exclusive scan of s_hist[0..511]
    const unsigned h = s_hist[t];
    unsigned incl = h;
#pragma unroll
    for (int off = 1; off < 64; off <<= 1) {
        const unsigned n = __shfl_up(incl, off, 64);
        if (lane >= off) incl += n;
    }
    if (lane == 63) s_wsum[wave] = incl;   // wave total
    __syncthreads();                                               // B3
    unsigned woff = 0;
#pragma unroll
    for (int w = 0; w < 8; ++w) woff += (w < wave) ? s_wsum[w] : 0u;
    const unsigned excl = woff + incl - h;

    unsigned* pf = prefix + (size_t)blk * PSTRIDE;
    if (t < NBINS) { s_cur[t] = excl; pf[t] = excl; }
    if (t == NBINS) pf[NBINS] = excl;      // total (bins >= 320 empty)
    if (t < 12) corner_out[blk * 12 + t] = s_corner[t];
    __syncthreads();                                               // B4

    // cur-ordered scatter into the chunk's private staged region
    float4* pbase = staged + (size_t)blk * PTS_PER_CHUNK;
#pragma unroll
    for (int j = 0; j < 4; ++j) {
        if (packed[j] != SENT) {
            const int bin = packed[j] >> 12;
            const unsigned p = atomicAdd(&s_cur[bin], 1u);
            pbase[p] = make_float4(__uint_as_float(packed[j]), R[j], G[j], B[j]);
        }
    }
}

// ---------------------------------------------------------------------------
// K2e: one block per (batch, row in {0,1023}, 32-px segment). Accumulates the
// segment's edge payloads + corner partials into 96 floats, stores edgebuf.
// ---------------------------------------------------------------------------
__global__ void __launch_bounds__(256)
edge_kernel(const float4* __restrict__ staged, const unsigned* __restrict__ prefix,
            const float* __restrict__ corner_out, float* __restrict__ edgebuf) {
    const int blk = blockIdx.x;            // b*64 + row*32 + seg
    const int b   = blk >> 6;
    const int row = (blk >> 5) & 1;
    const int seg = blk & 31;
    const int bin = 256 + row * 32 + seg;
    const int t   = threadIdx.x;

    __shared__ float    acc[96];           // [c][lx]
    __shared__ unsigned rs[128], re[128];

    if (t < 96) acc[t] = 0.0f;
    if (t < 128) rs[t]        = prefix[(size_t)(b * 128 + t) * PSTRIDE + bin];
    else         re[t - 128]  = prefix[(size_t)(b * 128 + (t - 128)) * PSTRIDE + bin + 1];
    __syncthreads();

    const int chunk = t & 127;
    const int sub   = t >> 7;
    const float4* pbase = staged + (size_t)(b * 128 + chunk) * PTS_PER_CHUNK;
    for (unsigned i = rs[chunk] + sub; i < re[chunk]; i += 2) {
        const float4 v = pbase[i];
        const int lx = (int)(__float_as_uint(v.x) & 1023u) - seg * 32;
        atomicAdd(&acc[lx],      v.y);
        atomicAdd(&acc[32 + lx], v.z);
        atomicAdd(&acc[64 + lx], v.w);
    }

    // corner fold: seg 0 owns px=0, seg 31 owns px=1023 of this row
    if (((seg == 0) | (seg == 31)) & (t < 128)) {
        const int ci = row * 2 + ((seg == 31) ? 1 : 0);
        const int lx = (seg == 31) ? 31 : 0;
        const float* cp = corner_out + (size_t)(b * 128 + t) * 12 + ci * 3;
        atomicAdd(&acc[lx],      cp[0]);
        atomicAdd(&acc[32 + lx], cp[1]);
        atomicAdd(&acc[64 + lx], cp[2]);
    }
    __syncthreads();

    if (t < 96) {
        const int c = t >> 5, lx = t & 31;
        edgebuf[((size_t)(b * 2 + row) * 3 + c) * 1024 + seg * 32 + lx] = acc[c * 32 + lx];
    }
}

// ---------------------------------------------------------------------------
// K2: one 512-thread block per (batch, 4-row band). 48 KB LDS stripe ->
// 3 blocks/CU (24 waves). Gather per-chunk runs (4 sub-readers each),
// LDS-atomic accumulate, fold edgebuf for bands 0/255, then fully linear
// nontemporal clipped float4 stores.
// ---------------------------------------------------------------------------
__global__ void __launch_bounds__(512)
accum_kernel(const float4* __restrict__ staged, const unsigned* __restrict__ prefix,
             const float* __restrict__ edgebuf, float* __restrict__ out) {
    const int bg   = blockIdx.x;           // 0..1023
    const int b    = bg >> 8;
    const int band = bg & 255;
    const int t    = threadIdx.x;

    __shared__ float    acc[3 * 4096];     // [c][ly*1024+px], 48 KB
    __shared__ unsigned rs[128], re[128];

    float4* acc4 = (float4*)acc;
    const float4 z4 = make_float4(0.f, 0.f, 0.f, 0.f);
#pragma unroll
    for (int i = 0; i < 6; ++i) acc4[i * 512 + t] = z4;
    if (t < 128)      rs[t]       = prefix[(size_t)(b * 128 + t) * PSTRIDE + band];
    else if (t < 256) re[t - 128] = prefix[(size_t)(b * 128 + (t - 128)) * PSTRIDE + band + 1];
    __syncthreads();

    const int chunk = t & 127;
    const int sub   = t >> 7;              // 0..3
    const float4* pbase = staged + (size_t)(b * 128 + chunk) * PTS_PER_CHUNK;
    for (unsigned i = rs[chunk] + sub; i < re[chunk]; i += 4) {
        const float4 v = pbase[i];
        const unsigned key = __float_as_uint(v.x);
        const unsigned idx = ((key >> 10) & 3u) * 1024 + (key & 1023u);
        atomicAdd(&acc[idx],        v.y);
        atomicAdd(&acc[4096 + idx], v.z);
        atomicAdd(&acc[8192 + idx], v.w);
    }
    __syncthreads();

    // fold edge rows: band 0 row ly=0 <- edgebuf row0; band 255 ly=3 <- row1023
    if (band == 0) {
        const float4* eb = (const float4*)(edgebuf + (size_t)(b * 2 + 0) * 3 * 1024);
        for (int k = t; k < 768; k += 512) {
            const int c = k >> 8, q = k & 255;
            const float4 e = eb[k];
            float4 a = acc4[c * 1024 + q];            // ly=0 row
            a.x += e.x; a.y += e.y; a.z += e.z; a.w += e.w;
            acc4[c * 1024 + q] = a;
        }
    } else if (band == 255) {
        const float4* eb = (const float4*)(edgebuf + (size_t)(b * 2 + 1) * 3 * 1024);
        for (int k = t; k < 768; k += 512) {
            const int c = k >> 8, q = k & 255;
            const float4 e = eb[k];
            float4 a = acc4[c * 1024 + 768 + q];      // ly=3 row
            a.x += e.x; a.y += e.y; a.z += e.z; a.w += e.w;
            acc4[c * 1024 + 768 + q] = a;
        }
    }
    __syncthreads();

    // fully linear clipped nontemporal stores (native vec type for builtin)
    float* ob = out + (size_t)b * 3 * IMG_HW + (size_t)band * 4096;
#pragma unroll
    for (int c = 0; c < 3; ++c) {
        nfloat4* dst = (nfloat4*)(ob + (size_t)c * IMG_HW);
#pragma unroll
        for (int k = 0; k < 2; ++k) {
            float4 v = acc4[c * 1024 + k * 512 + t];
            nfloat4 w;
            w.x = fminf(fmaxf(v.x, 0.f), 1.f);
            w.y = fminf(fmaxf(v.y, 0.f), 1.f);
            w.z = fminf(fmaxf(v.z, 0.f), 1.f);
            w.w = fminf(fmaxf(v.w, 0.f), 1.f);
            __builtin_nontemporal_store(w, &dst[k * 512 + t]);
        }
    }
}

extern "C" void kernel_launch(void* const* d_in, const int* in_sizes, int n_in,
                              void* d_out, int out_size, void* d_ws, size_t ws_size,
                              hipStream_t stream) {
    const float* uv  = (const float*)d_in[0];   // (4,14,512,512)
    const float* pos = (const float*)d_in[1];   // (4,3,512,512)
    float* out = (float*)d_out;                 // (4,3,1024,1024)

    char* ws = (char*)d_ws;
    float4*   staged     = (float4*)(ws);
    unsigned* prefix     = (unsigned*)(ws + PF_OFF);
    float*    corner_out = (float*)(ws + CO_OFF);
    float*    edgebuf    = (float*)(ws + EB_OFF);

    bin_kernel  <<<K1_BLOCKS, K1_THREADS, 0, stream>>>(uv, pos, staged, prefix,
                                                       corner_out);
    edge_kernel <<<BATCH * 64, 256, 0, stream>>>(staged, prefix, corner_out,
                                                 edgebuf);
    accum_kernel<<<BATCH * 256, 512, 0, stream>>>(staged, prefix, edgebuf, out);
}